// Round 10
// baseline (178.542 us; speedup 1.0000x reference)
//
#include <hip/hip_runtime.h>
#include <math.h>

typedef __attribute__((ext_vector_type(4))) float f32x4;
typedef __attribute__((ext_vector_type(2))) float f32x2;
typedef __attribute__((ext_vector_type(8))) short s16x8;

__device__ inline unsigned f2bf(float f) {
    unsigned u = __float_as_uint(f);
    u += 0x7FFFu + ((u >> 16) & 1u);
    return u >> 16;
}
// unpack a u32 holding two bf16 channels into {lo, hi} as f32 pair
__device__ inline f32x2 unpk2(unsigned u) {
    f32x2 r;
    r.x = __uint_as_float(u << 16);
    r.y = __uint_as_float(u & 0xFFFF0000u);
    return r;
}

// ---------------------------------------------------------------------------
// pack_all: blocks 0..511 pack_x; 512..767 Wp (per-o, fragment-linear);
// 768..799 Wo.  (unchanged from round 5 -- verified)
// ---------------------------------------------------------------------------
__global__ __launch_bounds__(256) void pack_all(const float* __restrict__ x,
                                                const float* __restrict__ w,
                                                const float* __restrict__ ow,
                                                unsigned* __restrict__ xt32,
                                                short* __restrict__ Wp,
                                                short* __restrict__ Wo)
{
    __shared__ float tile[256][33];
    const int tid = threadIdx.x;
    if (blockIdx.x < 512) {
        const int n = blockIdx.x >> 5, y = blockIdx.x & 31;
        const int b = n >> 3, ts = n & 7;
        const float* src = x + (((size_t)b * 256 * 8) + ts) * 1024 + y * 32;
        #pragma unroll
        for (int rep = 0; rep < 32; ++rep) {
            int c = rep * 8 + (tid >> 5);
            int ww = tid & 31;
            tile[c][ww] = src[(size_t)c * 8192 + ww];
        }
        __syncthreads();
        unsigned* dst = xt32 + ((size_t)n * 1024 + y * 32) * 128;
        #pragma unroll
        for (int rep = 0; rep < 16; ++rep) {
            int idx = rep * 256 + tid;
            int cp = idx & 127, ww = idx >> 7;
            unsigned lo = f2bf(tile[2 * cp][ww]);
            unsigned hi = f2bf(tile[2 * cp + 1][ww]);
            dst[(size_t)ww * 128 + cp] = lo | (hi << 16);
        }
    } else if (blockIdx.x < 768) {
        const int o = blockIdx.x - 512;
        float* lw = &tile[0][0];                     // 2304 floats, aliased
        for (int k = tid; k < 2304; k += 256) lw[k] = w[(size_t)o * 2304 + k];
        __syncthreads();
        const int oq = o >> 6, mt = (o >> 4) & 3, l15 = o & 15;
        for (int idx = tid; idx < 288; idx += 256) {
            int t = idx >> 5, cb = idx & 31;
            int quad = cb & 3, kc = (cb >> 2) & 1, k2 = cb >> 3;
            int lane = quad * 16 + l15;
            union { s16x8 v; short sh[8]; } u;
            #pragma unroll
            for (int c8 = 0; c8 < 8; ++c8)
                u.sh[c8] = (short)f2bf(lw[(cb * 8 + c8) * 9 + t]);
            size_t dst = ((((size_t)(t * 4 + oq) * 4 + mt) * 4 + k2) * 2 + kc) * 512
                       + lane * 8;
            *(s16x8*)(Wp + dst) = u.v;
        }
    } else {
        const int m = blockIdx.x - 768;              // < 32
        float* lw = &tile[0][0];
        if (m < 27) {
            for (int k = tid; k < 2304; k += 256) lw[k] = ow[(size_t)m * 2304 + k];
        }
        __syncthreads();
        #pragma unroll
        for (int t = 0; t < 9; ++t) {
            float v = (m < 27) ? lw[tid * 9 + t] : 0.f;
            Wo[t * 8192 + m * 256 + tid] = (short)f2bf(v);
        }
    }
}

// ---------------------------------------------------------------------------
// offsets_kernel: MFMA offset-conv + descriptor math -> global descW/descI.
// (unchanged from round 7 -- verified; 512 threads / 8 waves)
// ---------------------------------------------------------------------------
__global__ __launch_bounds__(512) void offsets_kernel(
    const short* __restrict__ xt, const short* __restrict__ Wo,
    const float* __restrict__ ob, float4* __restrict__ descW,
    int4* __restrict__ descI)
{
    __shared__ float pom[4][32][33];
    const int tid = threadIdx.x;
    const int bs = blockIdx.x;
    const int n = bs >> 5, ho = bs & 31;
    const int lane = tid & 63, wv = tid >> 6;
    const int nt = wv & 1, kq4 = wv >> 1;            // kq4 in 0..3
    const int l15 = lane & 15, quad = lane >> 4;
    const int pos = nt * 16 + l15;
    const short* xn = xt + (size_t)n * (1024 * 256);
    const s16x8 z8 = {0, 0, 0, 0, 0, 0, 0, 0};

    f32x4 oacc0 = {0, 0, 0, 0}, oacc1 = {0, 0, 0, 0};
    #pragma unroll
    for (int t = 0; t < 9; ++t) {
        const int ki = t / 3, kj = t - 3 * ki;       // compile-time
        int y = ho - 1 + ki;
        bool vy = (y >= 0) && (y < 32);
        int ycl = min(max(y, 0), 31);
        int xc = pos - 1 + kj;
        bool v = vy && (xc >= 0) && (xc < 32);
        int xcl = min(max(xc, 0), 31);
        const short* bp  = xn + (ycl * 32 + xcl) * 256;
        const short* ap0 = Wo + (t * 32 + l15) * 256;
        #pragma unroll
        for (int cc = 0; cc < 2; ++cc) {
            int c = kq4 * 64 + cc * 32 + quad * 8;
            s16x8 bfrag = *(const s16x8*)(bp + c);
            if (!v) bfrag = z8;
            s16x8 a0 = *(const s16x8*)(ap0 + c);
            s16x8 a1 = *(const s16x8*)(ap0 + 16 * 256 + c);
            oacc0 = __builtin_amdgcn_mfma_f32_16x16x32_bf16(a0, bfrag, oacc0, 0, 0, 0);
            oacc1 = __builtin_amdgcn_mfma_f32_16x16x32_bf16(a1, bfrag, oacc1, 0, 0, 0);
        }
    }
    #pragma unroll
    for (int r = 0; r < 4; ++r) {
        pom[kq4][quad * 4 + r][pos]      = oacc0[r];
        pom[kq4][16 + quad * 4 + r][pos] = oacc1[r];
    }
    __syncthreads();

    for (int s = tid; s < 288; s += 512) {
        int t = s >> 5, wo = s & 31;
        float dy = pom[0][2 * t][wo]     + pom[1][2 * t][wo]
                 + pom[2][2 * t][wo]     + pom[3][2 * t][wo]     + ob[2 * t];
        float dx = pom[0][2 * t + 1][wo] + pom[1][2 * t + 1][wo]
                 + pom[2][2 * t + 1][wo] + pom[3][2 * t + 1][wo] + ob[2 * t + 1];
        float mv = pom[0][18 + t][wo]    + pom[1][18 + t][wo]
                 + pom[2][18 + t][wo]    + pom[3][18 + t][wo]    + ob[18 + t];
        float mk = 1.0f / (1.0f + __expf(-mv));
        float py = dy + (float)(ho - 1 + t / 3);
        float px = dx + (float)(wo - 1 + t % 3);
        float y0f = floorf(py), x0f = floorf(px);
        float ty = py - y0f, tx = px - x0f;
        int y0 = (int)y0f, x0 = (int)x0f;
        int y1 = y0 + 1, x1 = x0 + 1;
        bool vy0 = (y0 >= 0) && (y0 < 32), vy1 = (y1 >= 0) && (y1 < 32);
        bool vx0 = (x0 >= 0) && (x0 < 32), vx1 = (x1 >= 0) && (x1 < 32);
        int cy0 = min(max(y0, 0), 31), cy1 = min(max(y1, 0), 31);
        int cx0 = min(max(x0, 0), 31), cx1 = min(max(x1, 0), 31);
        float b0 = (1.f - ty) * (1.f - tx) * mk * (float)(vy0 && vx0);
        float b1 = (1.f - ty) * tx         * mk * (float)(vy0 && vx1);
        float b2 = ty * (1.f - tx)         * mk * (float)(vy1 && vx0);
        float b3 = ty * tx                 * mk * (float)(vy1 && vx1);
        size_t base = (size_t)(n * 32 + ho) * 288 + s;
        descW[base] = make_float4(b0, b1, b2, b3);
        descI[base] = make_int4((cy0 * 32 + cx0) * 256, (cy0 * 32 + cx1) * 256,
                                (cy1 * 32 + cx0) * 256, (cy1 * 32 + cx1) * 256);
    }
}

// ---------------------------------------------------------------------------
// dcn_main<NK>: block = (n, ho, kq); NK consecutive 64-ch k2-blocks,
// 9*NK stages. XCD-chunked bid swizzle (verified round 9: FETCH 18.7->11.2MB).
// Round-10 change (ONLY): DEPTH-2 gather prefetch with PARITY-2 buffers.
// At stage s, repack consumes g[s&1] (issued at stage s-2), then the
// post-fence issue refills g[s&1] for stage s+2. Static s&1 indexing under
// the full unroll -> register-promotable (round 4's s%3 ring spilled; depth-2
// only ever needs 2 buffers since consume-then-refill is same-parity).
// In-flight window grows ~300cy -> >=1 full stage (~2000cy): covers HBM-miss
// gather latency, removing the per-stage repack-head stall.
// ---------------------------------------------------------------------------
template<int NK>
__global__ __launch_bounds__(256, 4) void dcn_main(
    const short* __restrict__ xt, const short* __restrict__ Wp,
    const float4* __restrict__ descW, const int4* __restrict__ descI,
    const float* __restrict__ bias, float* __restrict__ out,
    float* __restrict__ wsP)
{
    __shared__ short  sB[2][32 * 72];    // 32 pos x 64 c (+8 pad), 16B rows
    __shared__ float4 sdw[288];
    __shared__ int4   sdi[288];

    const int tid = threadIdx.x;
    constexpr int NQ = 4 / NK;                 // blocks per (n,ho)
    const int bid0 = blockIdx.x;
    const int bid = (bid0 & 7) * (64 * NQ) + (bid0 >> 3);  // XCD-chunked
    const int kq = bid & (NQ - 1);
    const int r  = bid / NQ;
    const int n = r >> 5, ho = r & 31;

    // stage descriptors for this (n, ho)
    {
        const float4* dW = descW + (size_t)(n * 32 + ho) * 288;
        const int4*   dI = descI + (size_t)(n * 32 + ho) * 288;
        for (int i = tid; i < 288; i += 256) { sdw[i] = dW[i]; sdi[i] = dI[i]; }
    }
    __syncthreads();

    const int oct = tid & 7, pos = tid >> 3;       // coalesced repack role
    const int oq = tid >> 6;                       // wave = oc-quarter
    const int lane = tid & 63, l15 = lane & 15, quad = lane >> 4;
    const short* xn = xt + (size_t)n * (1024 * 256);

    f32x4 acc[8];
    #pragma unroll
    for (int i = 0; i < 8; ++i) acc[i] = (f32x4){0, 0, 0, 0};

    uint4  g[2][4];     // parity-2 prefetched corner gathers (depth 2)
    float4 gw[2];       // matching bilinear weights

    // prologue: issue gathers for stages 0 AND 1 (depth-2 fill)
    #pragma unroll
    for (int ps = 0; ps < 2; ++ps) {
        const int tp = ps % 9;                     // == ps
        const int cbp = (kq * NK + ps / 9) * 64;   // == kq*NK*64
        gw[ps] = sdw[tp * 32 + pos];
        const int4 i4 = sdi[tp * 32 + pos];
        const int cc = cbp + oct * 8;
        g[ps][0] = *(const uint4*)(xn + i4.x + cc);
        g[ps][1] = *(const uint4*)(xn + i4.y + cc);
        g[ps][2] = *(const uint4*)(xn + i4.z + cc);
        g[ps][3] = *(const uint4*)(xn + i4.w + cc);
    }

    #pragma unroll
    for (int s = 0; s < 9 * NK; ++s) {
        const int cur = s & 1;
        const int t = s % 9;
        const int k2 = kq * NK + s / 9;            // channel 64-block index

        // ---- A-frags (fragment-linear, 16B/lane contiguous) issued FIRST -
        s16x8 afr[4][2];
        #pragma unroll
        for (int mt = 0; mt < 4; ++mt)
            #pragma unroll
            for (int kc = 0; kc < 2; ++kc)
                afr[mt][kc] = *(const s16x8*)(Wp +
                    ((((size_t)(t * 4 + oq) * 4 + mt) * 4 + k2) * 2 + kc) * 512
                    + lane * 8);

        // ---- repack prefetched gathers (issued at s-2) -> LDS ------------
        {
            const float4 w4 = gw[cur];
            const unsigned* p0 = (const unsigned*)&g[cur][0];
            const unsigned* p1 = (const unsigned*)&g[cur][1];
            const unsigned* p2 = (const unsigned*)&g[cur][2];
            const unsigned* p3 = (const unsigned*)&g[cur][3];
            union { s16x8 v; unsigned u[4]; } bu;
            #pragma unroll
            for (int d = 0; d < 4; ++d) {
                f32x2 a = w4.x * unpk2(p0[d]);
                a += w4.y * unpk2(p1[d]);
                a += w4.z * unpk2(p2[d]);
                a += w4.w * unpk2(p3[d]);
                asm("v_cvt_pk_bf16_f32 %0, %1, %2"
                    : "=v"(bu.u[d]) : "v"(a.x), "v"(a.y));
            }
            *(s16x8*)&sB[cur][pos * 72 + oct * 8] = bu.v;
        }

        // Fused LDS-drain + barrier (single asm: nothing schedulable between
        // the wait and the barrier). vmcnt stays in flight.
        asm volatile("s_waitcnt lgkmcnt(0)\n\ts_barrier" ::: "memory");
        __builtin_amdgcn_sched_barrier(0);

        // ---- issue gathers for stage s+2 into g[cur] (just consumed) -----
        if (s < 9 * NK - 2) {
            const int t2 = (s + 2) % 9;
            const int cb2 = (kq * NK + (s + 2) / 9) * 64;
            gw[cur] = sdw[t2 * 32 + pos];
            const int4 i4 = sdi[t2 * 32 + pos];
            const int cc = cb2 + oct * 8;
            g[cur][0] = *(const uint4*)(xn + i4.x + cc);
            g[cur][1] = *(const uint4*)(xn + i4.y + cc);
            g[cur][2] = *(const uint4*)(xn + i4.z + cc);
            g[cur][3] = *(const uint4*)(xn + i4.w + cc);
        }

        // ---- B-frags + MFMA ---------------------------------------------
        s16x8 bfr[2][2];
        #pragma unroll
        for (int nt = 0; nt < 2; ++nt)
            #pragma unroll
            for (int kc = 0; kc < 2; ++kc)
                bfr[nt][kc] = *(const s16x8*)
                    &sB[cur][(nt * 16 + l15) * 72 + kc * 32 + quad * 8];

        #pragma unroll
        for (int mt = 0; mt < 4; ++mt)
            #pragma unroll
            for (int nt = 0; nt < 2; ++nt) {
                acc[mt * 2 + nt] = __builtin_amdgcn_mfma_f32_16x16x32_bf16(
                    afr[mt][0], bfr[nt][0], acc[mt * 2 + nt], 0, 0, 0);
                acc[mt * 2 + nt] = __builtin_amdgcn_mfma_f32_16x16x32_bf16(
                    afr[mt][1], bfr[nt][1], acc[mt * 2 + nt], 0, 0, 0);
            }
    }

    // ---- epilogue: plain coalesced stores (no atomics) -------------------
    const int bb = n >> 3, ts = n & 7;
    if (kq == 0) {
        #pragma unroll
        for (int mt = 0; mt < 4; ++mt) {
            const float4 bv = *(const float4*)(bias + oq * 64 + mt * 16 + quad * 4);
            #pragma unroll
            for (int nt = 0; nt < 2; ++nt)
                #pragma unroll
                for (int rr = 0; rr < 4; ++rr) {
                    int oc = oq * 64 + mt * 16 + quad * 4 + rr;
                    int p  = nt * 16 + l15;
                    out[(((size_t)bb * 256 + oc) * 8 + ts) * 1024 + ho * 32 + p] =
                        acc[mt * 2 + nt][rr] + ((const float*)&bv)[rr];
                }
        }
    } else {
        float* wp1 = wsP + (size_t)(kq - 1) * 4194304
                         + (size_t)(n * 32 + ho) * 256 * 32;
        #pragma unroll
        for (int mt = 0; mt < 4; ++mt)
            #pragma unroll
            for (int nt = 0; nt < 2; ++nt)
                #pragma unroll
                for (int rr = 0; rr < 4; ++rr) {
                    int oc = oq * 64 + mt * 16 + quad * 4 + rr;
                    int p  = nt * 16 + l15;
                    wp1[oc * 32 + p] = acc[mt * 2 + nt][rr];
                }
    }
}

// ---------------------------------------------------------------------------
// reduce_out<NP>: out += sum of NP partials. Fully BW-bound. 4096 blocks.
// ---------------------------------------------------------------------------
template<int NP>
__global__ __launch_bounds__(256) void reduce_out(const float* __restrict__ wsP,
                                                  float4* __restrict__ out)
{
    int i = blockIdx.x * 256 + threadIdx.x;   // < 1048576 float4s
    int f = i * 4;
    int p  = f & 1023;             // ho*32 + pp
    int ts = (f >> 10) & 7;
    int oc = (f >> 13) & 255;
    int bb = f >> 21;
    int n = bb * 8 + ts;
    int ho = p >> 5, pp = p & 31;
    size_t base = ((size_t)(n * 32 + ho) * 256 + oc) * 32 + pp;
    float4 a = out[i];
    #pragma unroll
    for (int q = 0; q < NP; ++q) {
        const float4 w = *(const float4*)(wsP + (size_t)q * 4194304 + base);
        a.x += w.x; a.y += w.y; a.z += w.z; a.w += w.w;
    }
    out[i] = a;
}

// ---------------------------------------------------------------------------
extern "C" void kernel_launch(void* const* d_in, const int* in_sizes, int n_in,
                              void* d_out, int out_size, void* d_ws, size_t ws_size,
                              hipStream_t stream) {
    const float* x        = (const float*)d_in[0];
    const float* weight   = (const float*)d_in[1];
    const float* bias     = (const float*)d_in[2];
    const float* offset_w = (const float*)d_in[3];
    const float* offset_b = (const float*)d_in[4];

    char* ws = (char*)d_ws;
    short*  xt    = (short*)ws;                       ws += (size_t)16 * 1024 * 256 * 2; // 8.39 MB
    short*  Wp    = (short*)ws;                       ws += (size_t)9 * 256 * 256 * 2;   // 1.18 MB
    short*  Wo    = (short*)ws;                       ws += (size_t)9 * 32 * 256 * 2;    // 147 KB
    float4* descW = (float4*)ws;                      ws += (size_t)147456 * 16;         // 2.36 MB
    int4*   descI = (int4*)ws;                        ws += (size_t)147456 * 16;         // 2.36 MB
    float*  wsP   = (float*)ws;                       // 1 or 3 x 16.78 MB partials

    // 4-way K-split needs 14.43 MB fixed + 3*16.78 MB partials = 64.77 MB.
    const bool big = ws_size >= 64765952ULL;

    pack_all      <<<800,  256, 0, stream>>>(x, weight, offset_w, (unsigned*)xt, Wp, Wo);
    offsets_kernel<<<512,  512, 0, stream>>>(xt, Wo, offset_b, descW, descI);
    if (big) {
        dcn_main<1>   <<<2048, 256, 0, stream>>>(xt, Wp, descW, descI, bias, (float*)d_out, wsP);
        reduce_out<3> <<<4096, 256, 0, stream>>>(wsP, (float4*)d_out);
    } else {
        dcn_main<2>   <<<1024, 256, 0, stream>>>(xt, Wp, descW, descI, bias, (float*)d_out, wsP);
        reduce_out<1> <<<4096, 256, 0, stream>>>(wsP, (float4*)d_out);
    }
}

// Round 11
// 142.851 us; speedup vs baseline: 1.2498x; 1.2498x over previous
//
#include <hip/hip_runtime.h>
#include <math.h>

typedef __attribute__((ext_vector_type(4))) float f32x4;
typedef __attribute__((ext_vector_type(2))) float f32x2;
typedef __attribute__((ext_vector_type(8))) short s16x8;

__device__ inline unsigned f2bf(float f) {
    unsigned u = __float_as_uint(f);
    u += 0x7FFFu + ((u >> 16) & 1u);
    return u >> 16;
}
// unpack a u32 holding two bf16 channels into {lo, hi} as f32 pair
__device__ inline f32x2 unpk2(unsigned u) {
    f32x2 r;
    r.x = __uint_as_float(u << 16);
    r.y = __uint_as_float(u & 0xFFFF0000u);
    return r;
}

// ---------------------------------------------------------------------------
// pack_all: blocks 0..511 pack_x; 512..767 Wp (per-o, fragment-linear);
// 768..799 Wo.  (unchanged from round 5 -- verified)
// ---------------------------------------------------------------------------
__global__ __launch_bounds__(256) void pack_all(const float* __restrict__ x,
                                                const float* __restrict__ w,
                                                const float* __restrict__ ow,
                                                unsigned* __restrict__ xt32,
                                                short* __restrict__ Wp,
                                                short* __restrict__ Wo)
{
    __shared__ float tile[256][33];
    const int tid = threadIdx.x;
    if (blockIdx.x < 512) {
        const int n = blockIdx.x >> 5, y = blockIdx.x & 31;
        const int b = n >> 3, ts = n & 7;
        const float* src = x + (((size_t)b * 256 * 8) + ts) * 1024 + y * 32;
        #pragma unroll
        for (int rep = 0; rep < 32; ++rep) {
            int c = rep * 8 + (tid >> 5);
            int ww = tid & 31;
            tile[c][ww] = src[(size_t)c * 8192 + ww];
        }
        __syncthreads();
        unsigned* dst = xt32 + ((size_t)n * 1024 + y * 32) * 128;
        #pragma unroll
        for (int rep = 0; rep < 16; ++rep) {
            int idx = rep * 256 + tid;
            int cp = idx & 127, ww = idx >> 7;
            unsigned lo = f2bf(tile[2 * cp][ww]);
            unsigned hi = f2bf(tile[2 * cp + 1][ww]);
            dst[(size_t)ww * 128 + cp] = lo | (hi << 16);
        }
    } else if (blockIdx.x < 768) {
        const int o = blockIdx.x - 512;
        float* lw = &tile[0][0];                     // 2304 floats, aliased
        for (int k = tid; k < 2304; k += 256) lw[k] = w[(size_t)o * 2304 + k];
        __syncthreads();
        const int oq = o >> 6, mt = (o >> 4) & 3, l15 = o & 15;
        for (int idx = tid; idx < 288; idx += 256) {
            int t = idx >> 5, cb = idx & 31;
            int quad = cb & 3, kc = (cb >> 2) & 1, k2 = cb >> 3;
            int lane = quad * 16 + l15;
            union { s16x8 v; short sh[8]; } u;
            #pragma unroll
            for (int c8 = 0; c8 < 8; ++c8)
                u.sh[c8] = (short)f2bf(lw[(cb * 8 + c8) * 9 + t]);
            size_t dst = ((((size_t)(t * 4 + oq) * 4 + mt) * 4 + k2) * 2 + kc) * 512
                       + lane * 8;
            *(s16x8*)(Wp + dst) = u.v;
        }
    } else {
        const int m = blockIdx.x - 768;              // < 32
        float* lw = &tile[0][0];
        if (m < 27) {
            for (int k = tid; k < 2304; k += 256) lw[k] = ow[(size_t)m * 2304 + k];
        }
        __syncthreads();
        #pragma unroll
        for (int t = 0; t < 9; ++t) {
            float v = (m < 27) ? lw[tid * 9 + t] : 0.f;
            Wo[t * 8192 + m * 256 + tid] = (short)f2bf(v);
        }
    }
}

// ---------------------------------------------------------------------------
// offsets_kernel: MFMA offset-conv + descriptor math -> global descW/descI.
// (unchanged from round 7 -- verified; 512 threads / 8 waves)
// ---------------------------------------------------------------------------
__global__ __launch_bounds__(512) void offsets_kernel(
    const short* __restrict__ xt, const short* __restrict__ Wo,
    const float* __restrict__ ob, float4* __restrict__ descW,
    int4* __restrict__ descI)
{
    __shared__ float pom[4][32][33];
    const int tid = threadIdx.x;
    const int bs = blockIdx.x;
    const int n = bs >> 5, ho = bs & 31;
    const int lane = tid & 63, wv = tid >> 6;
    const int nt = wv & 1, kq4 = wv >> 1;            // kq4 in 0..3
    const int l15 = lane & 15, quad = lane >> 4;
    const int pos = nt * 16 + l15;
    const short* xn = xt + (size_t)n * (1024 * 256);
    const s16x8 z8 = {0, 0, 0, 0, 0, 0, 0, 0};

    f32x4 oacc0 = {0, 0, 0, 0}, oacc1 = {0, 0, 0, 0};
    #pragma unroll
    for (int t = 0; t < 9; ++t) {
        const int ki = t / 3, kj = t - 3 * ki;       // compile-time
        int y = ho - 1 + ki;
        bool vy = (y >= 0) && (y < 32);
        int ycl = min(max(y, 0), 31);
        int xc = pos - 1 + kj;
        bool v = vy && (xc >= 0) && (xc < 32);
        int xcl = min(max(xc, 0), 31);
        const short* bp  = xn + (ycl * 32 + xcl) * 256;
        const short* ap0 = Wo + (t * 32 + l15) * 256;
        #pragma unroll
        for (int cc = 0; cc < 2; ++cc) {
            int c = kq4 * 64 + cc * 32 + quad * 8;
            s16x8 bfrag = *(const s16x8*)(bp + c);
            if (!v) bfrag = z8;
            s16x8 a0 = *(const s16x8*)(ap0 + c);
            s16x8 a1 = *(const s16x8*)(ap0 + 16 * 256 + c);
            oacc0 = __builtin_amdgcn_mfma_f32_16x16x32_bf16(a0, bfrag, oacc0, 0, 0, 0);
            oacc1 = __builtin_amdgcn_mfma_f32_16x16x32_bf16(a1, bfrag, oacc1, 0, 0, 0);
        }
    }
    #pragma unroll
    for (int r = 0; r < 4; ++r) {
        pom[kq4][quad * 4 + r][pos]      = oacc0[r];
        pom[kq4][16 + quad * 4 + r][pos] = oacc1[r];
    }
    __syncthreads();

    for (int s = tid; s < 288; s += 512) {
        int t = s >> 5, wo = s & 31;
        float dy = pom[0][2 * t][wo]     + pom[1][2 * t][wo]
                 + pom[2][2 * t][wo]     + pom[3][2 * t][wo]     + ob[2 * t];
        float dx = pom[0][2 * t + 1][wo] + pom[1][2 * t + 1][wo]
                 + pom[2][2 * t + 1][wo] + pom[3][2 * t + 1][wo] + ob[2 * t + 1];
        float mv = pom[0][18 + t][wo]    + pom[1][18 + t][wo]
                 + pom[2][18 + t][wo]    + pom[3][18 + t][wo]    + ob[18 + t];
        float mk = 1.0f / (1.0f + __expf(-mv));
        float py = dy + (float)(ho - 1 + t / 3);
        float px = dx + (float)(wo - 1 + t % 3);
        float y0f = floorf(py), x0f = floorf(px);
        float ty = py - y0f, tx = px - x0f;
        int y0 = (int)y0f, x0 = (int)x0f;
        int y1 = y0 + 1, x1 = x0 + 1;
        bool vy0 = (y0 >= 0) && (y0 < 32), vy1 = (y1 >= 0) && (y1 < 32);
        bool vx0 = (x0 >= 0) && (x0 < 32), vx1 = (x1 >= 0) && (x1 < 32);
        int cy0 = min(max(y0, 0), 31), cy1 = min(max(y1, 0), 31);
        int cx0 = min(max(x0, 0), 31), cx1 = min(max(x1, 0), 31);
        float b0 = (1.f - ty) * (1.f - tx) * mk * (float)(vy0 && vx0);
        float b1 = (1.f - ty) * tx         * mk * (float)(vy0 && vx1);
        float b2 = ty * (1.f - tx)         * mk * (float)(vy1 && vx0);
        float b3 = ty * tx                 * mk * (float)(vy1 && vx1);
        size_t base = (size_t)(n * 32 + ho) * 288 + s;
        descW[base] = make_float4(b0, b1, b2, b3);
        descI[base] = make_int4((cy0 * 32 + cx0) * 256, (cy0 * 32 + cx1) * 256,
                                (cy1 * 32 + cx0) * 256, (cy1 * 32 + cx1) * 256);
    }
}

// ---------------------------------------------------------------------------
// dcn_single: 512 threads / 8 waves, ONE block per (n, ho), FULL K.
// Round-11: eliminates the kq split -> no ws1 partials, no reduce_out kernel
// (50 MB HBM RMW + a launch gap gone), dcn writes out once (16.8 vs 33.6 MB).
// Residency preserved: grid 512 x 8 waves = 2 blocks/CU = 16 waves/CU (same
// as round 9's 4x256); fences per CU halve (36 vs 72). Per-thread per-stage
// work is byte-identical to the verified round-9 structure: 18 stages of
// (tap t = s%9, 128-ch half h = s/9); each thread repacks 8 ch x 4 corners;
// 8 A-frag loads, 16 MFMA per wave per stage; same fused lgkmcnt(0)+s_barrier
// fence; same depth-1 s&1 register prefetch (depth-2 spills: rounds 4, 10).
// Wave wv owns oc [wv*32, wv*32+32): oq = wv>>1, layout-mt = (wv&1)*2 + mt.
// acc = 4 f32x4 (16 VGPR); worst-case live ~100 VGPR < 128 budget @ 4 w/SIMD.
// XCD-chunked bid swizzle kept (verified: FETCH 18.7 -> 11.2 MB).
// ---------------------------------------------------------------------------
__global__ __launch_bounds__(512, 4) void dcn_single(
    const short* __restrict__ xt, const short* __restrict__ Wp,
    const float4* __restrict__ descW, const int4* __restrict__ descI,
    const float* __restrict__ bias, float* __restrict__ out)
{
    __shared__ short  sB[2][32 * 136];   // 32 pos x 128 ch (+8 pad) = 17408 B
    __shared__ float4 sdw[288];
    __shared__ int4   sdi[288];

    const int tid = threadIdx.x;
    const int bid0 = blockIdx.x;
    const int bid = (bid0 & 7) * 64 + (bid0 >> 3);   // XCD-chunked (512%8==0)
    const int n = bid >> 5, ho = bid & 31;

    // stage descriptors for this (n, ho)
    {
        const float4* dW = descW + (size_t)(n * 32 + ho) * 288;
        const int4*   dI = descI + (size_t)(n * 32 + ho) * 288;
        for (int i = tid; i < 288; i += 512) { sdw[i] = dW[i]; sdi[i] = dI[i]; }
    }
    __syncthreads();

    const int oct16 = tid & 15, pos = tid >> 4;    // repack role (512 threads)
    const int wv = tid >> 6;                       // wave id 0..7
    const int oq = wv >> 1, mtb = (wv & 1) * 2;    // oc quarter + mt base
    const int lane = tid & 63, l15 = lane & 15, quad = lane >> 4;
    const short* xn = xt + (size_t)n * (1024 * 256);

    f32x4 acc[4];
    #pragma unroll
    for (int i = 0; i < 4; ++i) acc[i] = (f32x4){0, 0, 0, 0};

    uint4  g[2][4];     // depth-1 prefetched corner gathers (s&1 dbuf)
    float4 gw[2];       // matching bilinear weights

    // prologue: issue gathers for stage 0 (t=0, h=0)
    {
        gw[0] = sdw[pos];
        const int4 i4 = sdi[pos];
        const int cc = oct16 * 8;
        g[0][0] = *(const uint4*)(xn + i4.x + cc);
        g[0][1] = *(const uint4*)(xn + i4.y + cc);
        g[0][2] = *(const uint4*)(xn + i4.z + cc);
        g[0][3] = *(const uint4*)(xn + i4.w + cc);
    }

    #pragma unroll
    for (int s = 0; s < 18; ++s) {
        const int cur = s & 1, nxt = cur ^ 1;
        const int t = s % 9;
        const int h = s / 9;                       // 128-ch half

        // ---- A-frags (fragment-linear, 16B/lane contiguous) issued FIRST -
        s16x8 afr[2][4];
        #pragma unroll
        for (int mt = 0; mt < 2; ++mt)
            #pragma unroll
            for (int kp = 0; kp < 4; ++kp) {
                const int k2 = h * 2 + (kp >> 1), kc = kp & 1;
                afr[mt][kp] = *(const s16x8*)(Wp +
                    ((((size_t)(t * 4 + oq) * 4 + (mtb + mt)) * 4 + k2) * 2 + kc) * 512
                    + lane * 8);
            }

        // ---- repack prefetched gathers -> LDS (f32x2 + hw cvt_pk) -------
        {
            const float4 w4 = gw[cur];
            const unsigned* p0 = (const unsigned*)&g[cur][0];
            const unsigned* p1 = (const unsigned*)&g[cur][1];
            const unsigned* p2 = (const unsigned*)&g[cur][2];
            const unsigned* p3 = (const unsigned*)&g[cur][3];
            union { s16x8 v; unsigned u[4]; } bu;
            #pragma unroll
            for (int d = 0; d < 4; ++d) {
                f32x2 a = w4.x * unpk2(p0[d]);
                a += w4.y * unpk2(p1[d]);
                a += w4.z * unpk2(p2[d]);
                a += w4.w * unpk2(p3[d]);
                asm("v_cvt_pk_bf16_f32 %0, %1, %2"
                    : "=v"(bu.u[d]) : "v"(a.x), "v"(a.y));
            }
            *(s16x8*)&sB[cur][pos * 136 + oct16 * 8] = bu.v;
        }

        // Fused LDS-drain + barrier (single asm: nothing schedulable between
        // the wait and the barrier). vmcnt stays in flight.
        asm volatile("s_waitcnt lgkmcnt(0)\n\ts_barrier" ::: "memory");
        __builtin_amdgcn_sched_barrier(0);

        // ---- issue gathers for stage s+1 (stay in flight across MFMAs) --
        if (s < 17) {
            const int t1 = (s + 1) % 9;
            const int h1 = (s + 1) / 9;
            gw[nxt] = sdw[t1 * 32 + pos];
            const int4 i4 = sdi[t1 * 32 + pos];
            const int cc = h1 * 128 + oct16 * 8;
            g[nxt][0] = *(const uint4*)(xn + i4.x + cc);
            g[nxt][1] = *(const uint4*)(xn + i4.y + cc);
            g[nxt][2] = *(const uint4*)(xn + i4.z + cc);
            g[nxt][3] = *(const uint4*)(xn + i4.w + cc);
        }

        // ---- B-frags + MFMA ---------------------------------------------
        s16x8 bfr[2][4];
        #pragma unroll
        for (int nt = 0; nt < 2; ++nt)
            #pragma unroll
            for (int kp = 0; kp < 4; ++kp)
                bfr[nt][kp] = *(const s16x8*)
                    &sB[cur][(nt * 16 + l15) * 136 + kp * 32 + quad * 8];

        #pragma unroll
        for (int mt = 0; mt < 2; ++mt)
            #pragma unroll
            for (int nt = 0; nt < 2; ++nt)
                #pragma unroll
                for (int kp = 0; kp < 4; ++kp)
                    acc[mt * 2 + nt] = __builtin_amdgcn_mfma_f32_16x16x32_bf16(
                        afr[mt][kp], bfr[nt][kp], acc[mt * 2 + nt], 0, 0, 0);
    }

    // ---- epilogue: single coalesced store of bias+result ------------------
    const int bb = n >> 3, ts = n & 7;
    #pragma unroll
    for (int mt = 0; mt < 2; ++mt) {
        const float4 bv = *(const float4*)(bias + oq * 64 + (mtb + mt) * 16 + quad * 4);
        #pragma unroll
        for (int nt = 0; nt < 2; ++nt)
            #pragma unroll
            for (int rr = 0; rr < 4; ++rr) {
                int oc = oq * 64 + (mtb + mt) * 16 + quad * 4 + rr;
                int p  = nt * 16 + l15;
                out[(((size_t)bb * 256 + oc) * 8 + ts) * 1024 + ho * 32 + p] =
                    acc[mt * 2 + nt][rr] + ((const float*)&bv)[rr];
            }
    }
}

// ---------------------------------------------------------------------------
extern "C" void kernel_launch(void* const* d_in, const int* in_sizes, int n_in,
                              void* d_out, int out_size, void* d_ws, size_t ws_size,
                              hipStream_t stream) {
    const float* x        = (const float*)d_in[0];
    const float* weight   = (const float*)d_in[1];
    const float* bias     = (const float*)d_in[2];
    const float* offset_w = (const float*)d_in[3];
    const float* offset_b = (const float*)d_in[4];

    char* ws = (char*)d_ws;
    short*  xt    = (short*)ws;                       ws += (size_t)16 * 1024 * 256 * 2; // 8.39 MB
    short*  Wp    = (short*)ws;                       ws += (size_t)9 * 256 * 256 * 2;   // 1.18 MB
    short*  Wo    = (short*)ws;                       ws += (size_t)9 * 32 * 256 * 2;    // 147 KB
    float4* descW = (float4*)ws;                      ws += (size_t)147456 * 16;         // 2.36 MB
    int4*   descI = (int4*)ws;                        ws += (size_t)147456 * 16;         // 2.36 MB

    pack_all      <<<800, 256, 0, stream>>>(x, weight, offset_w, (unsigned*)xt, Wp, Wo);
    offsets_kernel<<<512, 512, 0, stream>>>(xt, Wo, offset_b, descW, descI);
    dcn_single    <<<512, 512, 0, stream>>>(xt, Wp, descW, descI, bias, (float*)d_out);
}

// Round 12
// 140.522 us; speedup vs baseline: 1.2706x; 1.0166x over previous
//
#include <hip/hip_runtime.h>
#include <math.h>

typedef __attribute__((ext_vector_type(4))) float f32x4;
typedef __attribute__((ext_vector_type(2))) float f32x2;
typedef __attribute__((ext_vector_type(8))) short s16x8;
typedef __attribute__((ext_vector_type(2))) _Float16 f16x2;
typedef __attribute__((ext_vector_type(8))) _Float16 f16x8;

// f32 -> f16 bits (RNE via hardware cvt)
__device__ inline unsigned short f2h(float f) {
    union { _Float16 h; unsigned short u; } c;
    c.h = (_Float16)f;
    return c.u;
}

// mfma wrapper: s16x8-held f16 bits -> f16 MFMA (same fragment layout as bf16)
__device__ inline f32x4 mfma16(s16x8 a, s16x8 b, f32x4 c) {
    union { s16x8 s; f16x8 h; } ua, ub;
    ua.s = a; ub.s = b;
    return __builtin_amdgcn_mfma_f32_16x16x32_f16(ua.h, ub.h, c, 0, 0, 0);
}

// ---------------------------------------------------------------------------
// pack_all: blocks 0..511 pack_x; 512..767 Wp (per-o, fragment-linear);
// 768..799 Wo.  Round-12: all packed values are f16 (was bf16) -- finer
// mantissa for unit-scale data AND enables v_pk_fma_f16 repack in dcn.
// ---------------------------------------------------------------------------
__global__ __launch_bounds__(256) void pack_all(const float* __restrict__ x,
                                                const float* __restrict__ w,
                                                const float* __restrict__ ow,
                                                unsigned* __restrict__ xt32,
                                                short* __restrict__ Wp,
                                                short* __restrict__ Wo)
{
    __shared__ float tile[256][33];
    const int tid = threadIdx.x;
    if (blockIdx.x < 512) {
        const int n = blockIdx.x >> 5, y = blockIdx.x & 31;
        const int b = n >> 3, ts = n & 7;
        const float* src = x + (((size_t)b * 256 * 8) + ts) * 1024 + y * 32;
        #pragma unroll
        for (int rep = 0; rep < 32; ++rep) {
            int c = rep * 8 + (tid >> 5);
            int ww = tid & 31;
            tile[c][ww] = src[(size_t)c * 8192 + ww];
        }
        __syncthreads();
        unsigned* dst = xt32 + ((size_t)n * 1024 + y * 32) * 128;
        #pragma unroll
        for (int rep = 0; rep < 16; ++rep) {
            int idx = rep * 256 + tid;
            int cp = idx & 127, ww = idx >> 7;
            unsigned lo = f2h(tile[2 * cp][ww]);
            unsigned hi = f2h(tile[2 * cp + 1][ww]);
            dst[(size_t)ww * 128 + cp] = lo | (hi << 16);
        }
    } else if (blockIdx.x < 768) {
        const int o = blockIdx.x - 512;
        float* lw = &tile[0][0];                     // 2304 floats, aliased
        for (int k = tid; k < 2304; k += 256) lw[k] = w[(size_t)o * 2304 + k];
        __syncthreads();
        const int oq = o >> 6, mt = (o >> 4) & 3, l15 = o & 15;
        for (int idx = tid; idx < 288; idx += 256) {
            int t = idx >> 5, cb = idx & 31;
            int quad = cb & 3, kc = (cb >> 2) & 1, k2 = cb >> 3;
            int lane = quad * 16 + l15;
            union { s16x8 v; short sh[8]; } u;
            #pragma unroll
            for (int c8 = 0; c8 < 8; ++c8)
                u.sh[c8] = (short)f2h(lw[(cb * 8 + c8) * 9 + t]);
            size_t dst = ((((size_t)(t * 4 + oq) * 4 + mt) * 4 + k2) * 2 + kc) * 512
                       + lane * 8;
            *(s16x8*)(Wp + dst) = u.v;
        }
    } else {
        const int m = blockIdx.x - 768;              // < 32
        float* lw = &tile[0][0];
        if (m < 27) {
            for (int k = tid; k < 2304; k += 256) lw[k] = ow[(size_t)m * 2304 + k];
        }
        __syncthreads();
        #pragma unroll
        for (int t = 0; t < 9; ++t) {
            float v = (m < 27) ? lw[tid * 9 + t] : 0.f;
            Wo[t * 8192 + m * 256 + tid] = (short)f2h(v);
        }
    }
}

// ---------------------------------------------------------------------------
// offsets_kernel: MFMA offset-conv + descriptor math -> global descW/descI.
// (structure unchanged from round 7 -- verified; 512 threads / 8 waves;
//  round-12: operands are f16, MFMA switched to the f16 variant -- identical
//  fragment layout and register counts.)
// ---------------------------------------------------------------------------
__global__ __launch_bounds__(512) void offsets_kernel(
    const short* __restrict__ xt, const short* __restrict__ Wo,
    const float* __restrict__ ob, float4* __restrict__ descW,
    int4* __restrict__ descI)
{
    __shared__ float pom[4][32][33];
    const int tid = threadIdx.x;
    const int bs = blockIdx.x;
    const int n = bs >> 5, ho = bs & 31;
    const int lane = tid & 63, wv = tid >> 6;
    const int nt = wv & 1, kq4 = wv >> 1;            // kq4 in 0..3
    const int l15 = lane & 15, quad = lane >> 4;
    const int pos = nt * 16 + l15;
    const short* xn = xt + (size_t)n * (1024 * 256);
    const s16x8 z8 = {0, 0, 0, 0, 0, 0, 0, 0};

    f32x4 oacc0 = {0, 0, 0, 0}, oacc1 = {0, 0, 0, 0};
    #pragma unroll
    for (int t = 0; t < 9; ++t) {
        const int ki = t / 3, kj = t - 3 * ki;       // compile-time
        int y = ho - 1 + ki;
        bool vy = (y >= 0) && (y < 32);
        int ycl = min(max(y, 0), 31);
        int xc = pos - 1 + kj;
        bool v = vy && (xc >= 0) && (xc < 32);
        int xcl = min(max(xc, 0), 31);
        const short* bp  = xn + (ycl * 32 + xcl) * 256;
        const short* ap0 = Wo + (t * 32 + l15) * 256;
        #pragma unroll
        for (int cc = 0; cc < 2; ++cc) {
            int c = kq4 * 64 + cc * 32 + quad * 8;
            s16x8 bfrag = *(const s16x8*)(bp + c);
            if (!v) bfrag = z8;
            s16x8 a0 = *(const s16x8*)(ap0 + c);
            s16x8 a1 = *(const s16x8*)(ap0 + 16 * 256 + c);
            oacc0 = mfma16(a0, bfrag, oacc0);
            oacc1 = mfma16(a1, bfrag, oacc1);
        }
    }
    #pragma unroll
    for (int r = 0; r < 4; ++r) {
        pom[kq4][quad * 4 + r][pos]      = oacc0[r];
        pom[kq4][16 + quad * 4 + r][pos] = oacc1[r];
    }
    __syncthreads();

    for (int s = tid; s < 288; s += 512) {
        int t = s >> 5, wo = s & 31;
        float dy = pom[0][2 * t][wo]     + pom[1][2 * t][wo]
                 + pom[2][2 * t][wo]     + pom[3][2 * t][wo]     + ob[2 * t];
        float dx = pom[0][2 * t + 1][wo] + pom[1][2 * t + 1][wo]
                 + pom[2][2 * t + 1][wo] + pom[3][2 * t + 1][wo] + ob[2 * t + 1];
        float mv = pom[0][18 + t][wo]    + pom[1][18 + t][wo]
                 + pom[2][18 + t][wo]    + pom[3][18 + t][wo]    + ob[18 + t];
        float mk = 1.0f / (1.0f + __expf(-mv));
        float py = dy + (float)(ho - 1 + t / 3);
        float px = dx + (float)(wo - 1 + t % 3);
        float y0f = floorf(py), x0f = floorf(px);
        float ty = py - y0f, tx = px - x0f;
        int y0 = (int)y0f, x0 = (int)x0f;
        int y1 = y0 + 1, x1 = x0 + 1;
        bool vy0 = (y0 >= 0) && (y0 < 32), vy1 = (y1 >= 0) && (y1 < 32);
        bool vx0 = (x0 >= 0) && (x0 < 32), vx1 = (x1 >= 0) && (x1 < 32);
        int cy0 = min(max(y0, 0), 31), cy1 = min(max(y1, 0), 31);
        int cx0 = min(max(x0, 0), 31), cx1 = min(max(x1, 0), 31);
        float b0 = (1.f - ty) * (1.f - tx) * mk * (float)(vy0 && vx0);
        float b1 = (1.f - ty) * tx         * mk * (float)(vy0 && vx1);
        float b2 = ty * (1.f - tx)         * mk * (float)(vy1 && vx0);
        float b3 = ty * tx                 * mk * (float)(vy1 && vx1);
        size_t base = (size_t)(n * 32 + ho) * 288 + s;
        descW[base] = make_float4(b0, b1, b2, b3);
        descI[base] = make_int4((cy0 * 32 + cx0) * 256, (cy0 * 32 + cx1) * 256,
                                (cy1 * 32 + cx0) * 256, (cy1 * 32 + cx1) * 256);
    }
}

// ---------------------------------------------------------------------------
// dcn_single: 512 threads / 8 waves, ONE block per (n, ho), FULL K.
// (verified round-11 structure: 18 stages of (tap, 128-ch half); fused
//  lgkmcnt(0)+s_barrier fence; depth-1 s&1 register prefetch -- depth-2
//  spills (rounds 4, 10); XCD-chunked bid swizzle.)
// Round-12 change (ONLY): f16 data path. The bilinear repack consumes packed
// f16 pairs DIRECTLY via v_pk_fma_f16 -- no unpack-to-f32, no cvt_pk:
// ~13 -> ~4 VALU ops per dword, ~35 fewer VALU ops/thread/stage on the
// dominant VALU stream. MFMA switched to f32_16x16x32_f16 (identical
// fragment layout / register counts; f32 accumulate unchanged).
// ---------------------------------------------------------------------------
__global__ __launch_bounds__(512, 4) void dcn_single(
    const short* __restrict__ xt, const short* __restrict__ Wp,
    const float4* __restrict__ descW, const int4* __restrict__ descI,
    const float* __restrict__ bias, float* __restrict__ out)
{
    __shared__ short  sB[2][32 * 136];   // 32 pos x 128 ch (+8 pad) = 17408 B
    __shared__ float4 sdw[288];
    __shared__ int4   sdi[288];

    const int tid = threadIdx.x;
    const int bid0 = blockIdx.x;
    const int bid = (bid0 & 7) * 64 + (bid0 >> 3);   // XCD-chunked (512%8==0)
    const int n = bid >> 5, ho = bid & 31;

    // stage descriptors for this (n, ho)
    {
        const float4* dW = descW + (size_t)(n * 32 + ho) * 288;
        const int4*   dI = descI + (size_t)(n * 32 + ho) * 288;
        for (int i = tid; i < 288; i += 512) { sdw[i] = dW[i]; sdi[i] = dI[i]; }
    }
    __syncthreads();

    const int oct16 = tid & 15, pos = tid >> 4;    // repack role (512 threads)
    const int wv = tid >> 6;                       // wave id 0..7
    const int oq = wv >> 1, mtb = (wv & 1) * 2;    // oc quarter + mt base
    const int lane = tid & 63, l15 = lane & 15, quad = lane >> 4;
    const short* xn = xt + (size_t)n * (1024 * 256);

    f32x4 acc[4];
    #pragma unroll
    for (int i = 0; i < 4; ++i) acc[i] = (f32x4){0, 0, 0, 0};

    uint4  g[2][4];     // depth-1 prefetched corner gathers (s&1 dbuf)
    float4 gw[2];       // matching bilinear weights

    // prologue: issue gathers for stage 0 (t=0, h=0)
    {
        gw[0] = sdw[pos];
        const int4 i4 = sdi[pos];
        const int cc = oct16 * 8;
        g[0][0] = *(const uint4*)(xn + i4.x + cc);
        g[0][1] = *(const uint4*)(xn + i4.y + cc);
        g[0][2] = *(const uint4*)(xn + i4.z + cc);
        g[0][3] = *(const uint4*)(xn + i4.w + cc);
    }

    #pragma unroll
    for (int s = 0; s < 18; ++s) {
        const int cur = s & 1, nxt = cur ^ 1;
        const int t = s % 9;
        const int h = s / 9;                       // 128-ch half

        // ---- A-frags (fragment-linear, 16B/lane contiguous) issued FIRST -
        s16x8 afr[2][4];
        #pragma unroll
        for (int mt = 0; mt < 2; ++mt)
            #pragma unroll
            for (int kp = 0; kp < 4; ++kp) {
                const int k2 = h * 2 + (kp >> 1), kc = kp & 1;
                afr[mt][kp] = *(const s16x8*)(Wp +
                    ((((size_t)(t * 4 + oq) * 4 + (mtb + mt)) * 4 + k2) * 2 + kc) * 512
                    + lane * 8);
            }

        // ---- repack prefetched gathers -> LDS (packed v_pk_fma_f16) ------
        {
            const float4 w4 = gw[cur];
            const _Float16 hx = (_Float16)w4.x, hy = (_Float16)w4.y;
            const _Float16 hz = (_Float16)w4.z, hw = (_Float16)w4.w;
            const f16x2 wx = {hx, hx}, wy = {hy, hy};
            const f16x2 wz = {hz, hz}, ww2 = {hw, hw};
            const unsigned* p0 = (const unsigned*)&g[cur][0];
            const unsigned* p1 = (const unsigned*)&g[cur][1];
            const unsigned* p2 = (const unsigned*)&g[cur][2];
            const unsigned* p3 = (const unsigned*)&g[cur][3];
            union { s16x8 v; unsigned u[4]; } bu;
            #pragma unroll
            for (int d = 0; d < 4; ++d) {
                union { unsigned u; f16x2 h; } c0, c1, c2, c3;
                c0.u = p0[d]; c1.u = p1[d]; c2.u = p2[d]; c3.u = p3[d];
                f16x2 a = wx * c0.h;
                a += wy * c1.h;
                a += wz * c2.h;
                a += ww2 * c3.h;
                union { f16x2 h; unsigned u; } r; r.h = a;
                bu.u[d] = r.u;
            }
            *(s16x8*)&sB[cur][pos * 136 + oct16 * 8] = bu.v;
        }

        // Fused LDS-drain + barrier (single asm: nothing schedulable between
        // the wait and the barrier). vmcnt stays in flight.
        asm volatile("s_waitcnt lgkmcnt(0)\n\ts_barrier" ::: "memory");
        __builtin_amdgcn_sched_barrier(0);

        // ---- issue gathers for stage s+1 (stay in flight across MFMAs) --
        if (s < 17) {
            const int t1 = (s + 1) % 9;
            const int h1 = (s + 1) / 9;
            gw[nxt] = sdw[t1 * 32 + pos];
            const int4 i4 = sdi[t1 * 32 + pos];
            const int cc = h1 * 128 + oct16 * 8;
            g[nxt][0] = *(const uint4*)(xn + i4.x + cc);
            g[nxt][1] = *(const uint4*)(xn + i4.y + cc);
            g[nxt][2] = *(const uint4*)(xn + i4.z + cc);
            g[nxt][3] = *(const uint4*)(xn + i4.w + cc);
        }

        // ---- B-frags + MFMA ---------------------------------------------
        s16x8 bfr[2][4];
        #pragma unroll
        for (int nt = 0; nt < 2; ++nt)
            #pragma unroll
            for (int kp = 0; kp < 4; ++kp)
                bfr[nt][kp] = *(const s16x8*)
                    &sB[cur][(nt * 16 + l15) * 136 + kp * 32 + quad * 8];

        #pragma unroll
        for (int mt = 0; mt < 2; ++mt)
            #pragma unroll
            for (int nt = 0; nt < 2; ++nt)
                #pragma unroll
                for (int kp = 0; kp < 4; ++kp)
                    acc[mt * 2 + nt] = mfma16(afr[mt][kp], bfr[nt][kp],
                                              acc[mt * 2 + nt]);
    }

    // ---- epilogue: single coalesced store of bias+result ------------------
    const int bb = n >> 3, ts = n & 7;
    #pragma unroll
    for (int mt = 0; mt < 2; ++mt) {
        const float4 bv = *(const float4*)(bias + oq * 64 + (mtb + mt) * 16 + quad * 4);
        #pragma unroll
        for (int nt = 0; nt < 2; ++nt)
            #pragma unroll
            for (int rr = 0; rr < 4; ++rr) {
                int oc = oq * 64 + (mtb + mt) * 16 + quad * 4 + rr;
                int p  = nt * 16 + l15;
                out[(((size_t)bb * 256 + oc) * 8 + ts) * 1024 + ho * 32 + p] =
                    acc[mt * 2 + nt][rr] + ((const float*)&bv)[rr];
            }
    }
}

// ---------------------------------------------------------------------------
extern "C" void kernel_launch(void* const* d_in, const int* in_sizes, int n_in,
                              void* d_out, int out_size, void* d_ws, size_t ws_size,
                              hipStream_t stream) {
    const float* x        = (const float*)d_in[0];
    const float* weight   = (const float*)d_in[1];
    const float* bias     = (const float*)d_in[2];
    const float* offset_w = (const float*)d_in[3];
    const float* offset_b = (const float*)d_in[4];

    char* ws = (char*)d_ws;
    short*  xt    = (short*)ws;                       ws += (size_t)16 * 1024 * 256 * 2; // 8.39 MB
    short*  Wp    = (short*)ws;                       ws += (size_t)9 * 256 * 256 * 2;   // 1.18 MB
    short*  Wo    = (short*)ws;                       ws += (size_t)9 * 32 * 256 * 2;    // 147 KB
    float4* descW = (float4*)ws;                      ws += (size_t)147456 * 16;         // 2.36 MB
    int4*   descI = (int4*)ws;                        ws += (size_t)147456 * 16;         // 2.36 MB

    pack_all      <<<800, 256, 0, stream>>>(x, weight, offset_w, (unsigned*)xt, Wp, Wo);
    offsets_kernel<<<512, 512, 0, stream>>>(xt, Wo, offset_b, descW, descI);
    dcn_single    <<<512, 512, 0, stream>>>(xt, Wp, descW, descI, bias, (float*)d_out);
}